// Round 6
// baseline (324.679 us; speedup 1.0000x reference)
//
#include <hip/hip_runtime.h>
#include <hip/hip_bf16.h>

// GQA block: B=2, S=2048, HID=2048, H=32, G=8, D=64, QPG=4.
// bf16 MFMA 16x16x32; fp32 accumulate. m97-style staging:
// global_load_lds width=16 into unpadded LDS with XOR swizzle
// (chunk_phys = chunk_log ^ (row&7); rows of 64 shorts = 8 chunks of 16B).
// Fragment layouts (HW-verified, learn_hip m89/m120):
//   A-frag:  A[m=lane&15][k=quad*8+j]
//   B-frag:  B[k=quad*8+j][n=lane&15]
//   C/D:     col(n)=lane&15, row(m)=quad*4+reg
// Attention: S^T = K Q^T, O^T = V^T P^T (softmax axis on regs+quads).
// No-max softmax (scores ~N(0,0.9), exp2 has 2^30 headroom, shift-invariant).
// l on the MFMA pipe via register ones-fragment. GQA: block's 4 waves = the 4
// heads of one kv-group sharing one K/V LDS tile; each wave owns 64 q.
// R6: K/V double-buffered (prefetch issued right after the single per-tile
// barrier -> vmcnt drain lands after ~700cyc of compute); P round-trip fused
// per q-set into an 8KB single-buffer (wave-private, no barrier).

typedef __attribute__((ext_vector_type(8))) short shortx8;
typedef __attribute__((ext_vector_type(4))) float floatx4;

#define SEQ 2048
#define QSC 0.1803368801111204f   // (1/8) * log2(e), folded into Wq/bq

#if __has_builtin(__builtin_amdgcn_exp2f)
#define EXP2F(x) __builtin_amdgcn_exp2f(x)
#else
#define EXP2F(x) __expf((x) * 0.6931471805599453f)
#endif

__device__ __forceinline__ unsigned short f2bf(float f) {      // RNE
  union { float f; unsigned u; } a; a.f = f;
  unsigned u = a.u;
  u += 0x7fffu + ((u >> 16) & 1u);
  return (unsigned short)(u >> 16);
}
__device__ __forceinline__ unsigned pk2f(float lo, float hi) { // fast round
  union { float f; unsigned u; } a, b; a.f = lo; b.f = hi;
  return ((a.u + 0x8000u) >> 16) | (((b.u + 0x8000u) >> 16) << 16);
}

// async global->LDS, 16B per lane; LDS dst = uniform base + lane*16
__device__ __forceinline__ void gload16(const unsigned short* g, unsigned short* l) {
  __builtin_amdgcn_global_load_lds((const __attribute__((address_space(1))) void*)g,
                                   (__attribute__((address_space(3))) void*)l, 16, 0, 0);
}

// ---------------- prep: cast x, transpose+cast all weights, concat bias ----------
// grid (64,64,6), block (32,8). z: 0=Wq(*QSC) 1=Wk 2=Wv 3=Wo 4=cast-x 5=bias.
__global__ void prep_kernel(const float* __restrict__ x,
                            const float* __restrict__ Wq, const float* __restrict__ Wk,
                            const float* __restrict__ Wv, const float* __restrict__ Wo,
                            const float* __restrict__ bq, const float* __restrict__ bk,
                            const float* __restrict__ bv,
                            unsigned short* __restrict__ WT,
                            unsigned short* __restrict__ WoT,
                            unsigned short* __restrict__ xb,
                            float* __restrict__ bqkv) {
  const int z = blockIdx.z;
  if (z == 4) {                       // cast x -> bf16, 2048 floats per block
    int fb = blockIdx.y * 64 + blockIdx.x;
    int tid = threadIdx.y * 32 + threadIdx.x;
    int i = fb * 2048 + tid * 8;
    float4 v0 = *(const float4*)(x + i);
    float4 v1 = *(const float4*)(x + i + 4);
    ushort4 o0, o1;
    o0.x = f2bf(v0.x); o0.y = f2bf(v0.y); o0.z = f2bf(v0.z); o0.w = f2bf(v0.w);
    o1.x = f2bf(v1.x); o1.y = f2bf(v1.y); o1.z = f2bf(v1.z); o1.w = f2bf(v1.w);
    *(ushort4*)(xb + i) = o0;
    *(ushort4*)(xb + i + 4) = o1;
    return;
  }
  if (z == 5) {                       // concat bias
    int fb = blockIdx.y * 64 + blockIdx.x;
    if (fb >= 12) return;
    int i = fb * 256 + threadIdx.y * 32 + threadIdx.x;
    if (i < 2048) bqkv[i] = bq[i] * QSC;
    else if (i < 2560) bqkv[i] = bk[i - 2048];
    else if (i < 3072) bqkv[i] = bv[i - 2560];
    return;
  }
  const float* W; unsigned short* D; int N; float sc = 1.f;
  if (z == 0)      { W = Wq; D = WT;               N = 2048; sc = QSC; }
  else if (z == 1) { W = Wk; D = WT + 2048 * 2048; N = 512; }
  else if (z == 2) { W = Wv; D = WT + 2560 * 2048; N = 512; }
  else             { W = Wo; D = WoT;              N = 2048; }
  if (blockIdx.x * 32 >= N) return;

  __shared__ float tile[32][33];
  int xx = blockIdx.x * 32 + threadIdx.x;
  int y0 = blockIdx.y * 32;
  for (int i = 0; i < 32; i += 8)
    tile[threadIdx.y + i][threadIdx.x] = W[(size_t)(y0 + threadIdx.y + i) * N + xx];
  __syncthreads();
  int nx = y0 + threadIdx.x;
  int ny = blockIdx.x * 32 + threadIdx.y;
  for (int i = 0; i < 32; i += 8)
    D[(size_t)(ny + i) * 2048 + nx] = f2bf(tile[threadIdx.x][threadIdx.y + i] * sc);
}

// ---------------- bf16 GEMM (m97 structure): C = A @ BT^T + bias ----------------
// 128x128 tile, BK=64, 4 waves (2x2), global_load_lds staging, swizzled LDS.
// MODE 0: fp32 out. MODE 2: QKV split (Q -> Cout bf16, K -> Kbuf, V -> Vt[gb][d][s]).
template <int MODE>
__global__ __launch_bounds__(256) void gemm_bt(const unsigned short* __restrict__ A,
                                               const unsigned short* __restrict__ BT,
                                               const float* __restrict__ bias,
                                               void* __restrict__ Cout,
                                               unsigned short* __restrict__ Kbuf,
                                               unsigned short* __restrict__ Vt,
                                               int M, int N, int K) {
  __shared__ __align__(16) unsigned short As[128 * 64];
  __shared__ __align__(16) unsigned short Bs[128 * 64];
  const int m0 = blockIdx.x * 128, n0 = blockIdx.y * 128;
  const int tid = threadIdx.x;
  const int lane = tid & 63, wave = tid >> 6;
  const int l15 = lane & 15, quad = lane >> 4;
  const int wm = (wave & 1) * 64, wn = (wave >> 1) * 64;

  const int r8 = lane >> 3;
  const int clog = (lane & 7) ^ r8;
  const unsigned short* aSrc = A + (size_t)(m0 + wave * 32 + r8) * K + clog * 8;
  const unsigned short* bSrc = BT + (size_t)(n0 + wave * 32 + r8) * K + clog * 8;
  unsigned short* aDst = &As[wave * 2048];
  unsigned short* bDst = &Bs[wave * 2048];

  const int s = l15 & 7;
  int aoff[4], boff[4];
#pragma unroll
  for (int i = 0; i < 4; i++) aoff[i] = (wm + i * 16 + l15) * 64 + (quad ^ s) * 8;
#pragma unroll
  for (int j = 0; j < 4; j++) boff[j] = (wn + j * 16 + l15) * 64 + (quad ^ s) * 8;

  floatx4 acc[4][4];
#pragma unroll
  for (int i = 0; i < 4; i++)
#pragma unroll
    for (int j = 0; j < 4; j++)
#pragma unroll
      for (int r = 0; r < 4; r++) acc[i][j][r] = 0.f;

  for (int k0 = 0; k0 < K; k0 += 64) {
    __syncthreads();
#pragma unroll
    for (int j = 0; j < 4; j++) {
      gload16(aSrc + (size_t)j * 8 * K + k0, aDst + j * 512);
      gload16(bSrc + (size_t)j * 8 * K + k0, bDst + j * 512);
    }
    __syncthreads();
    {
      shortx8 af[4], bf[4];
#pragma unroll
      for (int i = 0; i < 4; i++) af[i] = *(const shortx8*)&As[aoff[i]];
#pragma unroll
      for (int j = 0; j < 4; j++) bf[j] = *(const shortx8*)&Bs[boff[j]];
#pragma unroll
      for (int i = 0; i < 4; i++)
#pragma unroll
        for (int j = 0; j < 4; j++)
          acc[i][j] = __builtin_amdgcn_mfma_f32_16x16x32_bf16(af[i], bf[j], acc[i][j], 0, 0, 0);
#pragma unroll
      for (int i = 0; i < 4; i++) af[i] = *(const shortx8*)&As[aoff[i] ^ 32];
#pragma unroll
      for (int j = 0; j < 4; j++) bf[j] = *(const shortx8*)&Bs[boff[j] ^ 32];
#pragma unroll
      for (int i = 0; i < 4; i++)
#pragma unroll
        for (int j = 0; j < 4; j++)
          acc[i][j] = __builtin_amdgcn_mfma_f32_16x16x32_bf16(af[i], bf[j], acc[i][j], 0, 0, 0);
    }
  }

#pragma unroll
  for (int i = 0; i < 4; i++) {
#pragma unroll
    for (int j = 0; j < 4; j++) {
      int col = n0 + wn + j * 16 + l15;
      float bv = bias[col];
#pragma unroll
      for (int r = 0; r < 4; r++) {
        int row = m0 + wm + i * 16 + quad * 4 + r;
        float v = acc[i][j][r] + bv;
        if (MODE == 0) {
          ((float*)Cout)[(size_t)row * N + col] = v;
        } else {
          if (col < 2048) {
            ((unsigned short*)Cout)[(size_t)row * 2048 + col] = f2bf(v);
          } else if (col < 2560) {
            Kbuf[(size_t)row * 512 + (col - 2048)] = f2bf(v);
          } else {
            int g = (col - 2560) >> 6, d = (col - 2560) & 63;
            int b = row >> 11, sidx = row & 2047;
            Vt[(size_t)(((g << 1) | b) * 64 + d) * 2048 + sidx] = f2bf(v);
          }
        }
      }
    }
  }
}

// ---------------- flash attention (group-shared K/V, dbuf pipeline) ----------
// grid (S/64=32, G=8, B=2); wave w = head g*4+w. Each wave: 64 q rows as 4
// q-sets of 16. K/V tiles double-buffered; P single-buffered (wave-private).
__global__ __launch_bounds__(256, 2) void attn_kernel(const unsigned short* __restrict__ Qb,
                                                      const unsigned short* __restrict__ Kb,
                                                      const unsigned short* __restrict__ Vt,
                                                      unsigned short* __restrict__ O) {
  const int qt = blockIdx.x, g = blockIdx.y, b = blockIdx.z;
  const int tid = threadIdx.x;
  const int lane = tid & 63, wave = tid >> 6;
  const int h = g * 4 + wave;
  const int l15 = lane & 15, quad = lane >> 4;

  __shared__ __align__(16) unsigned short Ks[2][64 * 64];  // [t][d] swizzled, 2x8 KB
  __shared__ __align__(16) unsigned short Vs[2][64 * 64];  // [d][t] swizzled, 2x8 KB
  __shared__ __align__(16) unsigned short Ps[4 * 1024];    // per-wave 16q x 64t, 8 KB

  // Q fragments for 4 q-sets
  shortx8 qf[4][2];
  {
    const unsigned short* qp = Qb + (size_t)(b * SEQ + qt * 64 + l15) * 2048 + h * 64 + quad * 8;
#pragma unroll
    for (int a = 0; a < 4; a++) {
      qf[a][0] = *(const shortx8*)(qp + (size_t)a * 16 * 2048);
      qf[a][1] = *(const shortx8*)(qp + (size_t)a * 16 * 2048 + 32);
    }
  }

  // staging: wave stages rows wave*16..+15 of each tile (2 issues of 8 rows)
  const int r8 = lane >> 3;
  const int clog = (lane & 7) ^ r8;
  const unsigned short* kSrc = Kb + ((size_t)b * SEQ + wave * 16 + r8) * 512 + g * 64 + clog * 8;
  const unsigned short* vSrc = Vt + ((size_t)((g * 2 + b) * 64 + wave * 16 + r8)) * 2048 + clog * 8;

  const int s = l15 & 7;
  int foff[4];
#pragma unroll
  for (int i = 0; i < 4; i++) foff[i] = (i * 16 + l15) * 64 + ((quad ^ s) * 8);

  const int pbase = wave * 1024 + l15 * 64;
  int pw[4];
#pragma unroll
  for (int i = 0; i < 4; i++) pw[i] = (((i * 2 + (quad >> 1)) ^ s) * 8) + (quad & 1) * 4;
  int pr[2];
#pragma unroll
  for (int ks = 0; ks < 2; ks++) pr[ks] = ((ks * 4 + quad) ^ s) * 8;

  shortx8 ones;
#pragma unroll
  for (int j = 0; j < 8; j++) ones[j] = (short)0x3F80;     // bf16 1.0

  floatx4 oacc[4][4], lacc[4];
#pragma unroll
  for (int a = 0; a < 4; a++) {
#pragma unroll
    for (int r = 0; r < 4; r++) lacc[a][r] = 0.f;
#pragma unroll
    for (int nd = 0; nd < 4; nd++)
#pragma unroll
      for (int r = 0; r < 4; r++) oacc[a][nd][r] = 0.f;
  }

  // prologue: stage tile 0 into buffer 0
  {
    unsigned short* kD = &Ks[0][wave * 1024];
    unsigned short* vD = &Vs[0][wave * 1024];
    gload16(kSrc, kD);
    gload16(kSrc + (size_t)8 * 512, kD + 512);
    gload16(vSrc, vD);
    gload16(vSrc + (size_t)8 * 2048, vD + 512);
  }
  __syncthreads();

  for (int it = 0; it < SEQ / 64; it++) {
    const int p = it & 1;
    // prefetch next tile into the other buffer (async; drains at end-of-iter
    // barrier, after ~700cyc of compute below)
    if (it < SEQ / 64 - 1) {
      const size_t t1 = (size_t)(it + 1) * 64;
      unsigned short* kD = &Ks[p ^ 1][wave * 1024];
      unsigned short* vD = &Vs[p ^ 1][wave * 1024];
      gload16(kSrc + t1 * 512, kD);
      gload16(kSrc + (t1 + 8) * 512, kD + 512);
      gload16(vSrc + t1, vD);
      gload16(vSrc + (size_t)8 * 2048 + t1, vD + 512);
    }

    // K/V fragments for this tile (cached in regs, reused by all 4 q-sets)
    shortx8 kf[4][2], vf[4][2];
#pragma unroll
    for (int i = 0; i < 4; i++) {
      kf[i][0] = *(const shortx8*)&Ks[p][foff[i]];
      kf[i][1] = *(const shortx8*)&Ks[p][foff[i] ^ 32];
      vf[i][0] = *(const shortx8*)&Vs[p][foff[i]];
      vf[i][1] = *(const shortx8*)&Vs[p][foff[i] ^ 32];
    }

    // per q-set: QK^T -> exp -> P write -> P read -> PV (+ l row-sum)
#pragma unroll
    for (int a = 0; a < 4; a++) {
      floatx4 sc[4];
#pragma unroll
      for (int i = 0; i < 4; i++) {
        floatx4 c = {0.f, 0.f, 0.f, 0.f};
        c = __builtin_amdgcn_mfma_f32_16x16x32_bf16(kf[i][0], qf[a][0], c, 0, 0, 0);
        c = __builtin_amdgcn_mfma_f32_16x16x32_bf16(kf[i][1], qf[a][1], c, 0, 0, 0);
        sc[i] = c;
      }
#pragma unroll
      for (int i = 0; i < 4; i++) {
        float p0 = EXP2F(sc[i][0]), p1 = EXP2F(sc[i][1]);
        float p2 = EXP2F(sc[i][2]), p3 = EXP2F(sc[i][3]);
        uint2 w; w.x = pk2f(p0, p1); w.y = pk2f(p2, p3);
        *(uint2*)&Ps[pbase + pw[i]] = w;
      }
#pragma unroll
      for (int ks = 0; ks < 2; ks++) {
        shortx8 pf = *(const shortx8*)&Ps[pbase + pr[ks]];
#pragma unroll
        for (int nd = 0; nd < 4; nd++)
          oacc[a][nd] = __builtin_amdgcn_mfma_f32_16x16x32_bf16(vf[nd][ks], pf, oacc[a][nd], 0, 0, 0);
        lacc[a] = __builtin_amdgcn_mfma_f32_16x16x32_bf16(ones, pf, lacc[a], 0, 0, 0);
      }
    }
    __syncthreads();   // buffer p free for prefetch of tile it+2; prefetch p^1 drained
  }

  // epilogue: lacc rows identical -> l = lacc[a][0]; O^T cols q, rows d contiguous
#pragma unroll
  for (int a = 0; a < 4; a++) {
    float inv = 1.f / lacc[a][0];
    unsigned short* oPtr = O + (size_t)(b * SEQ + qt * 64 + a * 16 + l15) * 2048 + h * 64 + quad * 4;
#pragma unroll
    for (int nd = 0; nd < 4; nd++) {
      uint2 w;
      w.x = (unsigned)f2bf(oacc[a][nd][0] * inv) | ((unsigned)f2bf(oacc[a][nd][1] * inv) << 16);
      w.y = (unsigned)f2bf(oacc[a][nd][2] * inv) | ((unsigned)f2bf(oacc[a][nd][3] * inv) << 16);
      *(uint2*)(oPtr + nd * 16) = w;
    }
  }
}

extern "C" void kernel_launch(void* const* d_in, const int* in_sizes, int n_in,
                              void* d_out, int out_size, void* d_ws, size_t ws_size,
                              hipStream_t stream) {
  const float* x  = (const float*)d_in[0];
  const float* Wq = (const float*)d_in[1];
  const float* bq = (const float*)d_in[2];
  const float* Wk = (const float*)d_in[3];
  const float* bk = (const float*)d_in[4];
  const float* Wv = (const float*)d_in[5];
  const float* bv = (const float*)d_in[6];
  const float* Wo = (const float*)d_in[7];
  const float* bo = (const float*)d_in[8];
  float* out = (float*)d_out;

  // workspace layout (62,930,944 B total)
  char* ws = (char*)d_ws;
  unsigned short* WTall = (unsigned short*)ws;                          // [3072][2048] 12,582,912
  unsigned short* WoT   = (unsigned short*)(ws + 12582912);             // [2048][2048]  8,388,608
  float*          bqkv  = (float*)(ws + 20971520);                      // [3072] + pad      16384
  unsigned short* xb    = (unsigned short*)(ws + 20987904);             // [4096][2048] 16,777,216
  unsigned short* Qbuf  = (unsigned short*)(ws + 37765120);             // [4096][2048] 16,777,216
  unsigned short* Kbuf  = (unsigned short*)(ws + 54542336);             // [4096][512]   4,194,304
  unsigned short* Vt    = (unsigned short*)(ws + 58736640);             // [16][64][2048] 4,194,304
  unsigned short* Og    = xb;  // attention output reuses xb

  // 1. prep: cast x, transpose+cast weights (Wq pre-scaled), concat bias
  prep_kernel<<<dim3(64, 64, 6), dim3(32, 8), 0, stream>>>(
      x, Wq, Wk, Wv, Wo, bq, bk, bv, WTall, WoT, xb, bqkv);

  // 2. QKV projection: Q -> Qbuf, K -> Kbuf, V -> Vt (transposed)
  gemm_bt<2><<<dim3(32, 24), 256, 0, stream>>>(xb, WTall, bqkv, Qbuf, Kbuf, Vt, 4096, 3072, 2048);

  // 3. grouped flash attention -> Og [4096][2048] bf16
  attn_kernel<<<dim3(32, 8, 2), 256, 0, stream>>>(Qbuf, Kbuf, Vt, Og);

  // 4. output projection -> fp32 out
  gemm_bt<0><<<dim3(32, 16), 256, 0, stream>>>(Og, WoT, bo, out, nullptr, nullptr, 4096, 2048, 2048);
}

// Round 7
// 311.114 us; speedup vs baseline: 1.0436x; 1.0436x over previous
//
#include <hip/hip_runtime.h>
#include <hip/hip_bf16.h>

// GQA block: B=2, S=2048, HID=2048, H=32, G=8, D=64, QPG=4.
// bf16 MFMA 16x16x32; fp32 accumulate. m97-style staging:
// global_load_lds width=16 into unpadded LDS with XOR swizzle
// (chunk_phys = chunk_log ^ (row&7); rows of 64 shorts = 8 chunks of 16B).
// Fragment layouts (HW-verified, learn_hip m89/m120):
//   A-frag:  A[m=lane&15][k=quad*8+j]
//   B-frag:  B[k=quad*8+j][n=lane&15]
//   C/D:     col(n)=lane&15, row(m)=quad*4+reg
// Attention: S^T = K Q^T, O^T = V^T P^T (softmax axis on regs+quads).
// No-max softmax (scores ~N(0,0.9), exp2 has 2^30 headroom, shift-invariant).
// l on the MFMA pipe via register ones-fragment. GQA: block's 4 waves = the 4
// heads of one kv-group sharing one K/V LDS tile; each wave owns 64 q.
// R7: K/V dbuf (single barrier/tile) + PER-QSET P buffers (no WAR serialization
// across q-sets — R6's shared-P forced lgkm serialization) + phase-split PV.

typedef __attribute__((ext_vector_type(8))) short shortx8;
typedef __attribute__((ext_vector_type(4))) float floatx4;

#define SEQ 2048
#define QSC 0.1803368801111204f   // (1/8) * log2(e), folded into Wq/bq

#if __has_builtin(__builtin_amdgcn_exp2f)
#define EXP2F(x) __builtin_amdgcn_exp2f(x)
#else
#define EXP2F(x) __expf((x) * 0.6931471805599453f)
#endif

__device__ __forceinline__ unsigned short f2bf(float f) {      // RNE
  union { float f; unsigned u; } a; a.f = f;
  unsigned u = a.u;
  u += 0x7fffu + ((u >> 16) & 1u);
  return (unsigned short)(u >> 16);
}
__device__ __forceinline__ unsigned pk2f(float lo, float hi) { // fast round
  union { float f; unsigned u; } a, b; a.f = lo; b.f = hi;
  return ((a.u + 0x8000u) >> 16) | (((b.u + 0x8000u) >> 16) << 16);
}

// async global->LDS, 16B per lane; LDS dst = uniform base + lane*16
__device__ __forceinline__ void gload16(const unsigned short* g, unsigned short* l) {
  __builtin_amdgcn_global_load_lds((const __attribute__((address_space(1))) void*)g,
                                   (__attribute__((address_space(3))) void*)l, 16, 0, 0);
}

// ---------------- prep: cast x, transpose+cast all weights, concat bias ----------
// grid (64,64,6), block (32,8). z: 0=Wq(*QSC) 1=Wk 2=Wv 3=Wo 4=cast-x 5=bias.
__global__ void prep_kernel(const float* __restrict__ x,
                            const float* __restrict__ Wq, const float* __restrict__ Wk,
                            const float* __restrict__ Wv, const float* __restrict__ Wo,
                            const float* __restrict__ bq, const float* __restrict__ bk,
                            const float* __restrict__ bv,
                            unsigned short* __restrict__ WT,
                            unsigned short* __restrict__ WoT,
                            unsigned short* __restrict__ xb,
                            float* __restrict__ bqkv) {
  const int z = blockIdx.z;
  if (z == 4) {                       // cast x -> bf16, 2048 floats per block
    int fb = blockIdx.y * 64 + blockIdx.x;
    int tid = threadIdx.y * 32 + threadIdx.x;
    int i = fb * 2048 + tid * 8;
    float4 v0 = *(const float4*)(x + i);
    float4 v1 = *(const float4*)(x + i + 4);
    ushort4 o0, o1;
    o0.x = f2bf(v0.x); o0.y = f2bf(v0.y); o0.z = f2bf(v0.z); o0.w = f2bf(v0.w);
    o1.x = f2bf(v1.x); o1.y = f2bf(v1.y); o1.z = f2bf(v1.z); o1.w = f2bf(v1.w);
    *(ushort4*)(xb + i) = o0;
    *(ushort4*)(xb + i + 4) = o1;
    return;
  }
  if (z == 5) {                       // concat bias
    int fb = blockIdx.y * 64 + blockIdx.x;
    if (fb >= 12) return;
    int i = fb * 256 + threadIdx.y * 32 + threadIdx.x;
    if (i < 2048) bqkv[i] = bq[i] * QSC;
    else if (i < 2560) bqkv[i] = bk[i - 2048];
    else if (i < 3072) bqkv[i] = bv[i - 2560];
    return;
  }
  const float* W; unsigned short* D; int N; float sc = 1.f;
  if (z == 0)      { W = Wq; D = WT;               N = 2048; sc = QSC; }
  else if (z == 1) { W = Wk; D = WT + 2048 * 2048; N = 512; }
  else if (z == 2) { W = Wv; D = WT + 2560 * 2048; N = 512; }
  else             { W = Wo; D = WoT;              N = 2048; }
  if (blockIdx.x * 32 >= N) return;

  __shared__ float tile[32][33];
  int xx = blockIdx.x * 32 + threadIdx.x;
  int y0 = blockIdx.y * 32;
  for (int i = 0; i < 32; i += 8)
    tile[threadIdx.y + i][threadIdx.x] = W[(size_t)(y0 + threadIdx.y + i) * N + xx];
  __syncthreads();
  int nx = y0 + threadIdx.x;
  int ny = blockIdx.x * 32 + threadIdx.y;
  for (int i = 0; i < 32; i += 8)
    D[(size_t)(ny + i) * 2048 + nx] = f2bf(tile[threadIdx.x][threadIdx.y + i] * sc);
}

// ---------------- bf16 GEMM (m97 structure): C = A @ BT^T + bias ----------------
// 128x128 tile, BK=64, 4 waves (2x2), global_load_lds staging, swizzled LDS.
// MODE 0: fp32 out. MODE 2: QKV split (Q -> Cout bf16, K -> Kbuf, V -> Vt[gb][d][s]).
template <int MODE>
__global__ __launch_bounds__(256) void gemm_bt(const unsigned short* __restrict__ A,
                                               const unsigned short* __restrict__ BT,
                                               const float* __restrict__ bias,
                                               void* __restrict__ Cout,
                                               unsigned short* __restrict__ Kbuf,
                                               unsigned short* __restrict__ Vt,
                                               int M, int N, int K) {
  __shared__ __align__(16) unsigned short As[128 * 64];
  __shared__ __align__(16) unsigned short Bs[128 * 64];
  const int m0 = blockIdx.x * 128, n0 = blockIdx.y * 128;
  const int tid = threadIdx.x;
  const int lane = tid & 63, wave = tid >> 6;
  const int l15 = lane & 15, quad = lane >> 4;
  const int wm = (wave & 1) * 64, wn = (wave >> 1) * 64;

  const int r8 = lane >> 3;
  const int clog = (lane & 7) ^ r8;
  const unsigned short* aSrc = A + (size_t)(m0 + wave * 32 + r8) * K + clog * 8;
  const unsigned short* bSrc = BT + (size_t)(n0 + wave * 32 + r8) * K + clog * 8;
  unsigned short* aDst = &As[wave * 2048];
  unsigned short* bDst = &Bs[wave * 2048];

  const int s = l15 & 7;
  int aoff[4], boff[4];
#pragma unroll
  for (int i = 0; i < 4; i++) aoff[i] = (wm + i * 16 + l15) * 64 + (quad ^ s) * 8;
#pragma unroll
  for (int j = 0; j < 4; j++) boff[j] = (wn + j * 16 + l15) * 64 + (quad ^ s) * 8;

  floatx4 acc[4][4];
#pragma unroll
  for (int i = 0; i < 4; i++)
#pragma unroll
    for (int j = 0; j < 4; j++)
#pragma unroll
      for (int r = 0; r < 4; r++) acc[i][j][r] = 0.f;

  for (int k0 = 0; k0 < K; k0 += 64) {
    __syncthreads();
#pragma unroll
    for (int j = 0; j < 4; j++) {
      gload16(aSrc + (size_t)j * 8 * K + k0, aDst + j * 512);
      gload16(bSrc + (size_t)j * 8 * K + k0, bDst + j * 512);
    }
    __syncthreads();
    {
      shortx8 af[4], bf[4];
#pragma unroll
      for (int i = 0; i < 4; i++) af[i] = *(const shortx8*)&As[aoff[i]];
#pragma unroll
      for (int j = 0; j < 4; j++) bf[j] = *(const shortx8*)&Bs[boff[j]];
#pragma unroll
      for (int i = 0; i < 4; i++)
#pragma unroll
        for (int j = 0; j < 4; j++)
          acc[i][j] = __builtin_amdgcn_mfma_f32_16x16x32_bf16(af[i], bf[j], acc[i][j], 0, 0, 0);
#pragma unroll
      for (int i = 0; i < 4; i++) af[i] = *(const shortx8*)&As[aoff[i] ^ 32];
#pragma unroll
      for (int j = 0; j < 4; j++) bf[j] = *(const shortx8*)&Bs[boff[j] ^ 32];
#pragma unroll
      for (int i = 0; i < 4; i++)
#pragma unroll
        for (int j = 0; j < 4; j++)
          acc[i][j] = __builtin_amdgcn_mfma_f32_16x16x32_bf16(af[i], bf[j], acc[i][j], 0, 0, 0);
    }
  }

#pragma unroll
  for (int i = 0; i < 4; i++) {
#pragma unroll
    for (int j = 0; j < 4; j++) {
      int col = n0 + wn + j * 16 + l15;
      float bv = bias[col];
#pragma unroll
      for (int r = 0; r < 4; r++) {
        int row = m0 + wm + i * 16 + quad * 4 + r;
        float v = acc[i][j][r] + bv;
        if (MODE == 0) {
          ((float*)Cout)[(size_t)row * N + col] = v;
        } else {
          if (col < 2048) {
            ((unsigned short*)Cout)[(size_t)row * 2048 + col] = f2bf(v);
          } else if (col < 2560) {
            Kbuf[(size_t)row * 512 + (col - 2048)] = f2bf(v);
          } else {
            int g = (col - 2560) >> 6, d = (col - 2560) & 63;
            int b = row >> 11, sidx = row & 2047;
            Vt[(size_t)(((g << 1) | b) * 64 + d) * 2048 + sidx] = f2bf(v);
          }
        }
      }
    }
  }
}

// ---------------- flash attention (group-shared K/V, dbuf + per-qset P) ----------
// grid (S/64=32, G=8, B=2); wave w = head g*4+w. Each wave: 64 q rows as 4
// q-sets of 16. K/V dbuf (1 barrier/tile); P per-qset buffers (no WAR).
__global__ __launch_bounds__(256, 2) void attn_kernel(const unsigned short* __restrict__ Qb,
                                                      const unsigned short* __restrict__ Kb,
                                                      const unsigned short* __restrict__ Vt,
                                                      unsigned short* __restrict__ O) {
  const int qt = blockIdx.x, g = blockIdx.y, b = blockIdx.z;
  const int tid = threadIdx.x;
  const int lane = tid & 63, wave = tid >> 6;
  const int h = g * 4 + wave;
  const int l15 = lane & 15, quad = lane >> 4;

  __shared__ __align__(16) unsigned short Ks[2][64 * 64];  // [t][d] swizzled, 2x8 KB
  __shared__ __align__(16) unsigned short Vs[2][64 * 64];  // [d][t] swizzled, 2x8 KB
  __shared__ __align__(16) unsigned short Ps[4 * 4096];    // 4 waves x 4 qsets x 2KB

  // Q fragments for 4 q-sets
  shortx8 qf[4][2];
  {
    const unsigned short* qp = Qb + (size_t)(b * SEQ + qt * 64 + l15) * 2048 + h * 64 + quad * 8;
#pragma unroll
    for (int a = 0; a < 4; a++) {
      qf[a][0] = *(const shortx8*)(qp + (size_t)a * 16 * 2048);
      qf[a][1] = *(const shortx8*)(qp + (size_t)a * 16 * 2048 + 32);
    }
  }

  // staging: wave stages rows wave*16..+15 of each tile (2 issues of 8 rows)
  const int r8 = lane >> 3;
  const int clog = (lane & 7) ^ r8;
  const unsigned short* kSrc = Kb + ((size_t)b * SEQ + wave * 16 + r8) * 512 + g * 64 + clog * 8;
  const unsigned short* vSrc = Vt + ((size_t)((g * 2 + b) * 64 + wave * 16 + r8)) * 2048 + clog * 8;

  const int s = l15 & 7;
  int foff[4];
#pragma unroll
  for (int i = 0; i < 4; i++) foff[i] = (i * 16 + l15) * 64 + ((quad ^ s) * 8);

  const int pbase = wave * 4096 + l15 * 64;
  int pw[4];
#pragma unroll
  for (int i = 0; i < 4; i++) pw[i] = (((i * 2 + (quad >> 1)) ^ s) * 8) + (quad & 1) * 4;
  int pr[2];
#pragma unroll
  for (int ks = 0; ks < 2; ks++) pr[ks] = ((ks * 4 + quad) ^ s) * 8;

  shortx8 ones;
#pragma unroll
  for (int j = 0; j < 8; j++) ones[j] = (short)0x3F80;     // bf16 1.0

  floatx4 oacc[4][4], lacc[4];
#pragma unroll
  for (int a = 0; a < 4; a++) {
#pragma unroll
    for (int r = 0; r < 4; r++) lacc[a][r] = 0.f;
#pragma unroll
    for (int nd = 0; nd < 4; nd++)
#pragma unroll
      for (int r = 0; r < 4; r++) oacc[a][nd][r] = 0.f;
  }

  // prologue: stage tile 0 into buffer 0
  {
    unsigned short* kD = &Ks[0][wave * 1024];
    unsigned short* vD = &Vs[0][wave * 1024];
    gload16(kSrc, kD);
    gload16(kSrc + (size_t)8 * 512, kD + 512);
    gload16(vSrc, vD);
    gload16(vSrc + (size_t)8 * 2048, vD + 512);
  }
  __syncthreads();

  for (int it = 0; it < SEQ / 64; it++) {
    const int p = it & 1;
    // prefetch next tile into the other buffer (async; drained by the
    // end-of-iter barrier, ~1500 cyc of compute later)
    if (it < SEQ / 64 - 1) {
      const size_t t1 = (size_t)(it + 1) * 64;
      unsigned short* kD = &Ks[p ^ 1][wave * 1024];
      unsigned short* vD = &Vs[p ^ 1][wave * 1024];
      gload16(kSrc + t1 * 512, kD);
      gload16(kSrc + (t1 + 8) * 512, kD + 512);
      gload16(vSrc + t1, vD);
      gload16(vSrc + (size_t)8 * 2048 + t1, vD + 512);
    }

    // K fragments (reused by all 4 q-sets)
    shortx8 kf[4][2];
#pragma unroll
    for (int i = 0; i < 4; i++) {
      kf[i][0] = *(const shortx8*)&Ks[p][foff[i]];
      kf[i][1] = *(const shortx8*)&Ks[p][foff[i] ^ 32];
    }

    // phase 1: per q-set QK^T -> exp -> P write (per-qset buffers: qset a+1's
    // MFMAs overlap qset a's exp; no LDS WAR between q-sets)
#pragma unroll
    for (int a = 0; a < 4; a++) {
      floatx4 sc[4];
#pragma unroll
      for (int i = 0; i < 4; i++) {
        floatx4 c = {0.f, 0.f, 0.f, 0.f};
        c = __builtin_amdgcn_mfma_f32_16x16x32_bf16(kf[i][0], qf[a][0], c, 0, 0, 0);
        c = __builtin_amdgcn_mfma_f32_16x16x32_bf16(kf[i][1], qf[a][1], c, 0, 0, 0);
        sc[i] = c;
      }
#pragma unroll
      for (int i = 0; i < 4; i++) {
        float p0 = EXP2F(sc[i][0]), p1 = EXP2F(sc[i][1]);
        float p2 = EXP2F(sc[i][2]), p3 = EXP2F(sc[i][3]);
        uint2 w; w.x = pk2f(p0, p1); w.y = pk2f(p2, p3);
        *(uint2*)&Ps[pbase + a * 1024 + pw[i]] = w;
      }
    }

    // phase 2: V fragments, then PV + l row-sum for all q-sets (MFMA burst)
    shortx8 vf[4][2];
#pragma unroll
    for (int nd = 0; nd < 4; nd++) {
      vf[nd][0] = *(const shortx8*)&Vs[p][foff[nd]];
      vf[nd][1] = *(const shortx8*)&Vs[p][foff[nd] ^ 32];
    }
#pragma unroll
    for (int a = 0; a < 4; a++) {
#pragma unroll
      for (int ks = 0; ks < 2; ks++) {
        shortx8 pf = *(const shortx8*)&Ps[pbase + a * 1024 + pr[ks]];
#pragma unroll
        for (int nd = 0; nd < 4; nd++)
          oacc[a][nd] = __builtin_amdgcn_mfma_f32_16x16x32_bf16(vf[nd][ks], pf, oacc[a][nd], 0, 0, 0);
        lacc[a] = __builtin_amdgcn_mfma_f32_16x16x32_bf16(ones, pf, lacc[a], 0, 0, 0);
      }
    }
    __syncthreads();   // buffer p free; prefetch into p^1 drained
  }

  // epilogue: lacc rows identical -> l = lacc[a][0]; O^T cols q, rows d contiguous
#pragma unroll
  for (int a = 0; a < 4; a++) {
    float inv = 1.f / lacc[a][0];
    unsigned short* oPtr = O + (size_t)(b * SEQ + qt * 64 + a * 16 + l15) * 2048 + h * 64 + quad * 4;
#pragma unroll
    for (int nd = 0; nd < 4; nd++) {
      uint2 w;
      w.x = (unsigned)f2bf(oacc[a][nd][0] * inv) | ((unsigned)f2bf(oacc[a][nd][1] * inv) << 16);
      w.y = (unsigned)f2bf(oacc[a][nd][2] * inv) | ((unsigned)f2bf(oacc[a][nd][3] * inv) << 16);
      *(uint2*)(oPtr + nd * 16) = w;
    }
  }
}

extern "C" void kernel_launch(void* const* d_in, const int* in_sizes, int n_in,
                              void* d_out, int out_size, void* d_ws, size_t ws_size,
                              hipStream_t stream) {
  const float* x  = (const float*)d_in[0];
  const float* Wq = (const float*)d_in[1];
  const float* bq = (const float*)d_in[2];
  const float* Wk = (const float*)d_in[3];
  const float* bk = (const float*)d_in[4];
  const float* Wv = (const float*)d_in[5];
  const float* bv = (const float*)d_in[6];
  const float* Wo = (const float*)d_in[7];
  const float* bo = (const float*)d_in[8];
  float* out = (float*)d_out;

  // workspace layout (62,930,944 B total)
  char* ws = (char*)d_ws;
  unsigned short* WTall = (unsigned short*)ws;                          // [3072][2048] 12,582,912
  unsigned short* WoT   = (unsigned short*)(ws + 12582912);             // [2048][2048]  8,388,608
  float*          bqkv  = (float*)(ws + 20971520);                      // [3072] + pad      16384
  unsigned short* xb    = (unsigned short*)(ws + 20987904);             // [4096][2048] 16,777,216
  unsigned short* Qbuf  = (unsigned short*)(ws + 37765120);             // [4096][2048] 16,777,216
  unsigned short* Kbuf  = (unsigned short*)(ws + 54542336);             // [4096][512]   4,194,304
  unsigned short* Vt    = (unsigned short*)(ws + 58736640);             // [16][64][2048] 4,194,304
  unsigned short* Og    = xb;  // attention output reuses xb

  // 1. prep: cast x, transpose+cast weights (Wq pre-scaled), concat bias
  prep_kernel<<<dim3(64, 64, 6), dim3(32, 8), 0, stream>>>(
      x, Wq, Wk, Wv, Wo, bq, bk, bv, WTall, WoT, xb, bqkv);

  // 2. QKV projection: Q -> Qbuf, K -> Kbuf, V -> Vt (transposed)
  gemm_bt<2><<<dim3(32, 24), 256, 0, stream>>>(xb, WTall, bqkv, Qbuf, Kbuf, Vt, 4096, 3072, 2048);

  // 3. grouped flash attention -> Og [4096][2048] bf16
  attn_kernel<<<dim3(32, 8, 2), 256, 0, stream>>>(Qbuf, Kbuf, Vt, Og);

  // 4. output projection -> fp32 out
  gemm_bt<0><<<dim3(32, 16), 256, 0, stream>>>(Og, WoT, bo, out, nullptr, nullptr, 4096, 2048, 2048);
}